// Round 19
// baseline (127.693 us; speedup 1.0000x reference)
//
#include <hip/hip_runtime.h>
#include <math.h>

#define BB 4
#define LL 1024
#define DD 256
#define NT (BB*LL)          // 4096 tokens
#define LN_EPS 1e-5f

#define SEG 128             // segment length (8 per batch)
#define WARM 32             // warmup steps; df^32 = 4e-5 -> truncation negligible

// workspace layout (floats). band FIRST so staging overrun lands in owned
// regions. bf16 staging buffers overlay regions dead at their time of use.
#define OFF_BAND 0                      // NT*4 floats: 16 per 4-token group
#define OFF_PQ   (8*NT)
#define OFF_PK   (OFF_PQ + NT*DD)
#define OFF_V    (OFF_PK + NT*DD)       // becomes beta*v after phi (in-place)
#define OFF_Y    (OFF_V + NT*DD)        // also q staging before phi
#define OFF_LNY  (OFF_Y + NT*DD)        // also k staging before phi
#define OFF_BETA (OFF_LNY + NT*DD)

typedef __attribute__((ext_vector_type(8))) short short8;
typedef __attribute__((ext_vector_type(4))) float f32x4;
typedef __attribute__((ext_vector_type(2))) float f32x2;

// Builtin DPP add (compiler inserts DPP hazard nops) — off the hot path.
#define DPP_ADD(x, ctrl) ((x) + __uint_as_float(__builtin_amdgcn_update_dpp( \
        0u, __float_as_uint(x), (ctrl), 0xf, 0xf, true)))
#define DPP_RED6(x) x = DPP_ADD(x, 0x111); x = DPP_ADD(x, 0x112); \
                    x = DPP_ADD(x, 0x114); x = DPP_ADD(x, 0x118); \
                    x = DPP_ADD(x, 0x142); x = DPP_ADD(x, 0x143);

__device__ __forceinline__ float dot4f(float4 a, float4 b) {
    return fmaf(a.x, b.x, a.y * b.y) + fmaf(a.z, b.z, a.w * b.w);
}
__device__ __forceinline__ float rdl63(float x) {
    return __uint_as_float((unsigned)__builtin_amdgcn_readlane(__float_as_uint(x), 63));
}
__device__ __forceinline__ unsigned short f2bf(float f) {
    unsigned u = __float_as_uint(f);
    unsigned r = (u + 0x7fffu + ((u >> 16) & 1u)) >> 16;   // RNE
    return (unsigned short)r;
}

// Packed fp32 (VOP3P, dual-SIMD) — hipcc won't auto-generate these.
__device__ __forceinline__ f32x2 pk_mul(f32x2 a, f32x2 b) {
    f32x2 d; asm("v_pk_mul_f32 %0, %1, %2" : "=v"(d) : "v"(a), "v"(b)); return d;
}
__device__ __forceinline__ f32x2 pk_fma(f32x2 a, f32x2 b, f32x2 c) {
    f32x2 d; asm("v_pk_fma_f32 %0, %1, %2, %3" : "=v"(d) : "v"(a), "v"(b), "v"(c)); return d;
}
__device__ __forceinline__ float dot4pk(f32x2 w01, f32x2 w23, float4 b) {
    f32x2 blo = {b.x, b.y}, bhi = {b.z, b.w};
    f32x2 t = pk_mul(w01, blo);
    t = pk_fma(w23, bhi, t);
    return t.x + t.y;
}

// ---------------------------------------------------------------------------
// cast_all: x -> bf16 xb (+ betas via DPP reduce), Wq/Wk/Wv -> bf16 wb.
// ---------------------------------------------------------------------------
__global__ __launch_bounds__(256)
void cast_all_kernel(const float* __restrict__ x, const float* __restrict__ Wq,
                     const float* __restrict__ Wk, const float* __restrict__ Wv,
                     const float* __restrict__ beta_w, const float* __restrict__ beta_b,
                     unsigned short* __restrict__ xb, unsigned short* __restrict__ wb,
                     float* __restrict__ betas)
{
    int b = blockIdx.x;
    if (b < 1024) {
        const int lane = threadIdx.x & 63;
        const int t = b * 4 + (threadIdx.x >> 6);
        size_t idx = (size_t)b * 1024 + (size_t)threadIdx.x * 4;
        float4 v = *(const float4*)(x + idx);
        ushort4 o;
        o.x = f2bf(v.x); o.y = f2bf(v.y); o.z = f2bf(v.z); o.w = f2bf(v.w);
        *(ushort4*)(xb + idx) = o;
        float4 bw4 = *(const float4*)(beta_w + lane * 4);
        float bd = dot4f(v, bw4);
        DPP_RED6(bd)
        if (lane == 63) betas[t] = 1.f / (1.f + expf(-(bd + beta_b[0])));
    } else {
        int wsel = (b - 1024) >> 6;
        const float* src = (wsel == 0) ? Wq : (wsel == 1) ? Wk : Wv;
        unsigned short* dst = wb + (size_t)wsel * 65536;
        size_t idx = (size_t)((b - 1024) & 63) * 1024 + (size_t)threadIdx.x * 4;
        float4 v = *(const float4*)(src + idx);
        ushort4 o;
        o.x = f2bf(v.x); o.y = f2bf(v.y); o.z = f2bf(v.z); o.w = f2bf(v.w);
        *(ushort4*)(dst + idx) = o;
    }
}

__global__ __launch_bounds__(256)
void cast_wo_kernel(const float* __restrict__ Wo, unsigned short* __restrict__ wob)
{
    size_t idx = (size_t)blockIdx.x * 1024 + (size_t)threadIdx.x * 4;
    float4 v = *(const float4*)(Wo + idx);
    ushort4 o;
    o.x = f2bf(v.x); o.y = f2bf(v.y); o.z = f2bf(v.z); o.w = f2bf(v.w);
    *(ushort4*)(wob + idx) = o;
}

// ---------------------------------------------------------------------------
// MFMA bf16 GEMM (as R12-R18).
// ---------------------------------------------------------------------------
__device__ __forceinline__
void gemm_bf16_body(const unsigned short* __restrict__ A,
                    const unsigned short* __restrict__ W,
                    const float* __restrict__ bias, float* __restrict__ C,
                    int tile_m, int tile_n)
{
    const int w = threadIdx.x >> 6;
    const int l = threadIdx.x & 63;
    const int wm = (w >> 1) * 32, wn = (w & 1) * 32;
    const int kb = (l >> 4) * 8;

    const unsigned short* Ap = A + (size_t)(tile_m + wm + (l & 15)) * DD + kb;
    const unsigned short* Wp = W + (size_t)(tile_n + wn + (l & 15)) * DD + kb;

    f32x4 acc00 = {0.f,0.f,0.f,0.f}, acc01 = {0.f,0.f,0.f,0.f};
    f32x4 acc10 = {0.f,0.f,0.f,0.f}, acc11 = {0.f,0.f,0.f,0.f};

    #pragma unroll
    for (int ks = 0; ks < DD; ks += 32) {
        short8 a0 = *(const short8*)(Ap + ks);
        short8 a1 = *(const short8*)(Ap + 16*DD + ks);
        short8 b0 = *(const short8*)(Wp + ks);
        short8 b1 = *(const short8*)(Wp + 16*DD + ks);
        acc00 = __builtin_amdgcn_mfma_f32_16x16x32_bf16(a0, b0, acc00, 0, 0, 0);
        acc01 = __builtin_amdgcn_mfma_f32_16x16x32_bf16(a0, b1, acc01, 0, 0, 0);
        acc10 = __builtin_amdgcn_mfma_f32_16x16x32_bf16(a1, b0, acc10, 0, 0, 0);
        acc11 = __builtin_amdgcn_mfma_f32_16x16x32_bf16(a1, b1, acc11, 0, 0, 0);
    }

    const int r0 = (l >> 4) * 4;
    const int c0 = l & 15;
    #pragma unroll
    for (int i = 0; i < 2; ++i) {
        #pragma unroll
        for (int j = 0; j < 2; ++j) {
            const f32x4 a = (i==0) ? (j==0?acc00:acc01) : (j==0?acc10:acc11);
            int row = tile_m + wm + i*16 + r0;
            int col = tile_n + wn + j*16 + c0;
            float bv = bias ? bias[col] : 0.f;
            #pragma unroll
            for (int r = 0; r < 4; ++r)
                C[(size_t)(row + r) * DD + col] = a[r] + bv;
        }
    }
}

__global__ __launch_bounds__(256)
void gemm_qkv_bf16_kernel(const unsigned short* __restrict__ xb,
                          const unsigned short* __restrict__ wb,
                          float* __restrict__ q, float* __restrict__ k,
                          float* __restrict__ v)
{
    const unsigned short* W = wb + (size_t)blockIdx.z * 65536;
    float* C = (blockIdx.z == 0) ? q : (blockIdx.z == 1) ? k : v;
    gemm_bf16_body(xb, W, nullptr, C, blockIdx.x * 64, blockIdx.y * 64);
}

__global__ __launch_bounds__(256)
void gemm_out_bf16_kernel(const unsigned short* __restrict__ lnyb,
                          const unsigned short* __restrict__ wob,
                          const float* __restrict__ bo, float* __restrict__ C)
{
    gemm_bf16_body(lnyb, wob, bo, C, blockIdx.x * 64, blockIdx.y * 64);
}

// ---------------------------------------------------------------------------
// phi: wave-per-token. pq = LN(elu(q)+1), pk = LN(elu(k)+1), v *= beta.
// ---------------------------------------------------------------------------
__global__ __launch_bounds__(256)
void phi_kernel(const float* __restrict__ q, const float* __restrict__ k,
                float* __restrict__ v, const float* __restrict__ betas,
                const float* __restrict__ lnp_g, const float* __restrict__ lnp_b,
                float* __restrict__ pq, float* __restrict__ pk)
{
    const int t = blockIdx.x * 4 + (threadIdx.x >> 6);
    const int lane = threadIdx.x & 63;
    const int col = lane * 4;
    const size_t base = (size_t)t * DD + col;

    float4 q4 = *(const float4*)(q + base);
    float4 k4 = *(const float4*)(k + base);

    float4 eq, ek;
    eq.x = q4.x > 0.f ? q4.x + 1.f : expf(q4.x);
    eq.y = q4.y > 0.f ? q4.y + 1.f : expf(q4.y);
    eq.z = q4.z > 0.f ? q4.z + 1.f : expf(q4.z);
    eq.w = q4.w > 0.f ? q4.w + 1.f : expf(q4.w);
    ek.x = k4.x > 0.f ? k4.x + 1.f : expf(k4.x);
    ek.y = k4.y > 0.f ? k4.y + 1.f : expf(k4.y);
    ek.z = k4.z > 0.f ? k4.z + 1.f : expf(k4.z);
    ek.w = k4.w > 0.f ? k4.w + 1.f : expf(k4.w);

    float s0 = eq.x + eq.y + eq.z + eq.w;
    float s1 = dot4f(eq, eq);
    float s2 = ek.x + ek.y + ek.z + ek.w;
    float s3 = dot4f(ek, ek);

    DPP_RED6(s0) DPP_RED6(s1) DPP_RED6(s2) DPP_RED6(s3)
    float T0 = rdl63(s0), T1 = rdl63(s1), T2 = rdl63(s2), T3 = rdl63(s3);

    float mu_q = T0 * (1.f/DD);
    float rs_q = rsqrtf(T1 * (1.f/DD) - mu_q*mu_q + LN_EPS);
    float mu_k = T2 * (1.f/DD);
    float rs_k = rsqrtf(T3 * (1.f/DD) - mu_k*mu_k + LN_EPS);
    float beta = betas[t];

    float4 g4 = *(const float4*)(lnp_g + col);
    float4 b4 = *(const float4*)(lnp_b + col);
    float4 oq, ok;
    oq.x = (eq.x - mu_q) * rs_q * g4.x + b4.x;
    oq.y = (eq.y - mu_q) * rs_q * g4.y + b4.y;
    oq.z = (eq.z - mu_q) * rs_q * g4.z + b4.z;
    oq.w = (eq.w - mu_q) * rs_q * g4.w + b4.w;
    ok.x = (ek.x - mu_k) * rs_k * g4.x + b4.x;
    ok.y = (ek.y - mu_k) * rs_k * g4.y + b4.y;
    ok.z = (ek.z - mu_k) * rs_k * g4.z + b4.z;
    ok.w = (ek.w - mu_k) * rs_k * g4.w + b4.w;
    *(float4*)(pq + base) = oq;
    *(float4*)(pk + base) = ok;

    float4 v4 = *(const float4*)(v + base);
    v4.x *= beta; v4.y *= beta; v4.z *= beta; v4.w *= beta;
    *(float4*)(v + base) = v4;
}

// ---------------------------------------------------------------------------
// band (depth-3, group-packed): for each 4-token group, a 16-float record:
// [0..3]  fG  = {G1(t1), G1(t2), G2(t2), G1(t3)}
// [4..7]  fG2 = {G2(t3), G3(t3), H1(t1), H1(t2)}
// [8..11] fH  = {H2(t2), H1(t3), H2(t3), H3(t3)}
// [12..15]fB  = {beta0, beta1, beta2, beta3}
// G_m = df^{m-1}(pk[t-m].pk[t]), H_m = df^{m-1}(pk[t-m].pq[t]); 0 if t-m<0.
// One wave per token; lane 63 scatter-writes its token's slots.
// ---------------------------------------------------------------------------
__global__ __launch_bounds__(256)
void band_kernel(const float* __restrict__ pq, const float* __restrict__ pk,
                 const float* __restrict__ betas, const float* __restrict__ decay,
                 float* __restrict__ band)
{
    const int wv = threadIdx.x >> 6, lane = threadIdx.x & 63;
    const int g = blockIdx.x * 4 + wv;       // global token 0..NT-1
    const int tt = g & (LL - 1);             // token index within batch
    const int col = lane * 4;
    const float df = 1.f / (1.f + expf(-decay[0]));

    float4 kv = *(const float4*)(pk + (size_t)g * DD + col);
    float4 qv = *(const float4*)(pq + (size_t)g * DD + col);

    float gg1 = 0.f, hh1 = 0.f, gg2 = 0.f, hh2 = 0.f, gg3 = 0.f, hh3 = 0.f;
    if (tt >= 1) { float4 km = *(const float4*)(pk + (size_t)(g-1) * DD + col);
                   gg1 = dot4f(km, kv); hh1 = dot4f(km, qv); }
    if (tt >= 2) { float4 km = *(const float4*)(pk + (size_t)(g-2) * DD + col);
                   gg2 = dot4f(km, kv); hh2 = dot4f(km, qv); }
    if (tt >= 3) { float4 km = *(const float4*)(pk + (size_t)(g-3) * DD + col);
                   gg3 = dot4f(km, kv); hh3 = dot4f(km, qv); }

    DPP_RED6(gg1) DPP_RED6(hh1) DPP_RED6(gg2) DPP_RED6(hh2) DPP_RED6(gg3) DPP_RED6(hh3)

    if (lane == 63) {
        float* rec = band + (size_t)(g >> 2) * 16;
        const int j = g & 3;
        float G1 = gg1, G2 = df*gg2, G3 = df*df*gg3;
        float H1 = hh1, H2 = df*hh2, H3 = df*df*hh3;
        float beta = betas[g];
        if (j == 0)      { rec[12] = beta; }
        else if (j == 1) { rec[0] = G1; rec[6] = H1; rec[13] = beta; }
        else if (j == 2) { rec[1] = G1; rec[2] = G2; rec[7] = H1; rec[8] = H2;
                           rec[14] = beta; }
        else             { rec[3] = G1; rec[4] = G2; rec[5] = G3; rec[9] = H1;
                           rec[10] = H2; rec[11] = H3; rec[15] = beta; }
    }
}

// ---------------------------------------------------------------------------
// Segmented fast-weight recurrence, 8 waves/SIMD, LDS-shared q/k, STEP4:
// one barrier per 4 tokens (R18 had one per 2). ALL per-step operands are
// loaded at macro top and dead by macro bottom (kk re-read from LDS at acc),
// so no cross-step register buffers exist — avoids the (256,8) spill trap.
// Depth-3 recursion (R12-proven) from the 16-float group band record.
// LDS 2 x 8 x 256 floats = 16KB; 8 blocks/CU -> 128KB.
// ---------------------------------------------------------------------------
#define RED_ROUND8(mod, pre)                                                    \
    asm(pre                                                                     \
        "v_add_f32 %0, %0, %0 " mod " bound_ctrl:0\n\t"                         \
        "v_add_f32 %1, %1, %1 " mod " bound_ctrl:0\n\t"                         \
        "v_add_f32 %2, %2, %2 " mod " bound_ctrl:0\n\t"                         \
        "v_add_f32 %3, %3, %3 " mod " bound_ctrl:0\n\t"                         \
        "v_add_f32 %4, %4, %4 " mod " bound_ctrl:0\n\t"                         \
        "v_add_f32 %5, %5, %5 " mod " bound_ctrl:0\n\t"                         \
        "v_add_f32 %6, %6, %6 " mod " bound_ctrl:0\n\t"                         \
        "v_add_f32 %7, %7, %7 " mod " bound_ctrl:0"                             \
        : "+v"(s0), "+v"(s1), "+v"(s2), "+v"(s3),                               \
          "+v"(p0), "+v"(p1), "+v"(p2), "+v"(p3));

#define RED_ROUND4S(mod, pre)                                                   \
    asm(pre                                                                     \
        "v_add_f32 %0, %0, %0 " mod " bound_ctrl:0\n\t"                         \
        "v_add_f32 %1, %1, %1 " mod " bound_ctrl:0\n\t"                         \
        "v_add_f32 %2, %2, %2 " mod " bound_ctrl:0\n\t"                         \
        "v_add_f32 %3, %3, %3 " mod " bound_ctrl:0"                             \
        : "+v"(s0), "+v"(s1), "+v"(s2), "+v"(s3));

#define STEP4L(ST)                                                              \
  {                                                                             \
    const float* LB = &ldsb[cur][0][0];                                         \
    float4 qq0 = *(const float4*)(LB +        col4);                            \
    float4 qq1 = *(const float4*)(LB + 256  + col4);                            \
    float4 qq2 = *(const float4*)(LB + 512  + col4);                            \
    float4 qq3 = *(const float4*)(LB + 768  + col4);                            \
    float4 kk0 = *(const float4*)(LB + 1024 + col4);                            \
    float4 kk1 = *(const float4*)(LB + 1280 + col4);                            \
    float4 kk2 = *(const float4*)(LB + 1536 + col4);                            \
    float4 kk3 = *(const float4*)(LB + 1792 + col4);                            \
    float s0 = dot4pk(w01, w23, kk0),       p0 = dot4pk(w01, w23, qq0);         \
    float s1 = dot4pk(w01, w23, kk1) * df,  p1 = dot4pk(w01, w23, qq1) * df;    \
    float s2 = dot4pk(w01, w23, kk2) * df2, p2 = dot4pk(w01, w23, qq2) * df2;   \
    float s3 = dot4pk(w01, w23, kk3) * df3, p3 = dot4pk(w01, w23, qq3) * df3;   \
    float4 fG  = *(const float4*)(bdc + gbof);                                  \
    float4 fG2 = *(const float4*)(bdc + gbof + 16);                             \
    float4 fH  = *(const float4*)(bdc + gbof + 32);                             \
    float4 fB  = *(const float4*)(bdc + gbof + 48);                             \
    gbof += 64u;                                                                \
    float vA0 = *(const float*)(vbc + vof);                                     \
    float vA1 = *(const float*)(vbc + vof + 1024);                              \
    float vA2 = *(const float*)(vbc + vof + 2048);                              \
    float vA3 = *(const float*)(vbc + vof + 3072);                              \
    vof += 4096u;                                                               \
    float4 sq = *(const float4*)(pqc + gqof);                                   \
    float4 sk = *(const float4*)(pkc + gkof);                                   \
    gqof += 4096u; gkof += 4096u;                                               \
    RED_ROUND8("row_shr:1",   "s_nop 1\n\t")                                    \
    RED_ROUND8("row_shr:2",   "")                                               \
    RED_ROUND8("row_shr:4",   "")                                               \
    RED_ROUND8("row_shr:8",   "")                                               \
    RED_ROUND8("row_bcast:15","")                                               \
    RED_ROUND8("row_bcast:31","")                                               \
    asm volatile("s_nop 1");                                                    \
    /* depth-3 in-lane recursion: valid in lane 63 (band/v wave-uniform) */     \
    const float u0v = fmaf(-fB.x, s0, vA0);                                     \
    const float rr0 = p0;                                                       \
    const float vr1 = fmaf(fG.x, u0v, s1);                                      \
    const float rr1 = fmaf(fG2.z, u0v, p1);                                     \
    const float u1v = fmaf(-fB.y, vr1, vA1);                                    \
    const float vr2 = fmaf(fG.y, u1v, fmaf(fG.z, u0v, s2));                     \
    const float rr2 = fmaf(fG2.w, u1v, fmaf(fH.x, u0v, p2));                    \
    const float u2v = fmaf(-fB.z, vr2, vA2);                                    \
    const float vr3 = fmaf(fG.w, u2v, fmaf(fG2.x, u1v, fmaf(fG2.y, u0v, s3)));  \
    const float rr3 = fmaf(fH.y, u2v, fmaf(fH.z, u1v, fmaf(fH.w, u0v, p3)));    \
    const float u3v = fmaf(-fB.w, vr3, vA3);                                    \
    const float u0 = rdl63(u0v), u1 = rdl63(u1v);                               \
    const float u2 = rdl63(u2v), u3 = rdl63(u3v);                               \
    /* re-read k rows from LDS (kk regs dead after dots) */                     \
    float4 ka0 = *(const float4*)(LB + 1024 + col4);                            \
    float4 ka1 = *(const float4*)(LB + 1280 + col4);                            \
    float4 ka2 = *(const float4*)(LB + 1536 + col4);                            \
    float4 ka3 = *(const float4*)(LB + 1792 + col4);                            \
    float4 acc;                                                                 \
    acc.x = u0*ka0.x; acc.y = u0*ka0.y; acc.z = u0*ka0.z; acc.w = u0*ka0.w;     \
    acc.x = fmaf(df, acc.x, u1*ka1.x); acc.y = fmaf(df, acc.y, u1*ka1.y);       \
    acc.z = fmaf(df, acc.z, u1*ka1.z); acc.w = fmaf(df, acc.w, u1*ka1.w);       \
    acc.x = fmaf(df, acc.x, u2*ka2.x); acc.y = fmaf(df, acc.y, u2*ka2.y);       \
    acc.z = fmaf(df, acc.z, u2*ka2.z); acc.w = fmaf(df, acc.w, u2*ka2.w);       \
    acc.x = fmaf(df, acc.x, u3*ka3.x); acc.y = fmaf(df, acc.y, u3*ka3.y);       \
    acc.z = fmaf(df, acc.z, u3*ka3.z); acc.w = fmaf(df, acc.w, u3*ka3.w);       \
    { f32x2 a01 = {acc.x, acc.y}, a23 = {acc.z, acc.w};                         \
      w01 = pk_fma(df4p, w01, a01); w23 = pk_fma(df4p, w23, a23); }             \
    if (ST) {                                                                   \
        if (lane == 63) {                                                       \
            *(float*)(ybc + yof)        = rr0;                                  \
            *(float*)(ybc + yof + 1024) = rr1;                                  \
            *(float*)(ybc + yof + 2048) = rr2;                                  \
            *(float*)(ybc + yof + 3072) = rr3;                                  \
        }                                                                       \
        yof += 4096u;                                                           \
    }                                                                           \
    *(float4*)(&ldsb[cur ^ 1][sid][0]     + col4) = sq;                         \
    *(float4*)(&ldsb[cur ^ 1][4 + sid][0] + col4) = sk;                         \
    __syncthreads();                                                            \
    cur ^= 1;                                                                   \
    __builtin_amdgcn_sched_barrier(0);                                          \
  }

// Warmup: W-evolution only (no q dots / p chains / stores); still stages.
#define STEP4LW()                                                               \
  {                                                                             \
    const float* LB = &ldsb[cur][0][0];                                         \
    float4 kk0 = *(const float4*)(LB + 1024 + col4);                            \
    float4 kk1 = *(const float4*)(LB + 1280 + col4);                            \
    float4 kk2 = *(const float4*)(LB + 1536 + col4);                            \
    float4 kk3 = *(const float4*)(LB + 1792 + col4);                            \
    float s0 = dot4pk(w01, w23, kk0);                                           \
    float s1 = dot4pk(w01, w23, kk1) * df;                                      \
    float s2 = dot4pk(w01, w23, kk2) * df2;                                     \
    float s3 = dot4pk(w01, w23, kk3) * df3;                                     \
    float4 fG  = *(const float4*)(bdc + gbof);                                  \
    float4 fG2 = *(const float4*)(bdc + gbof + 16);                             \
    float4 fB  = *(const float4*)(bdc + gbof + 48);                             \
    gbof += 64u;                                                                \
    float vA0 = *(const float*)(vbc + vof);                                     \
    float vA1 = *(const float*)(vbc + vof + 1024);                              \
    float vA2 = *(const float*)(vbc + vof + 2048);                              \
    float vA3 = *(const float*)(vbc + vof + 3072);                              \
    vof += 4096u;                                                               \
    float4 sq = *(const float4*)(pqc + gqof);                                   \
    float4 sk = *(const float4*)(pkc + gkof);                                   \
    gqof += 4096u; gkof += 4096u;                                               \
    RED_ROUND4S("row_shr:1",   "s_nop 1\n\t")                                   \
    RED_ROUND4S("row_shr:2",   "")                                              \
    RED_ROUND4S("row_shr:4",   "")                                              \
    RED_ROUND4S("row_shr:8",   "")                                              \
    RED_ROUND4S("row_bcast:15","")                                              \
    RED_ROUND4S("row_bcast:31","")                                              \
    asm volatile("s_nop 1");                                                    \
    const float u0v = fmaf(-fB.x, s0, vA0);                                     \
    const float vr1 = fmaf(fG.x, u0v, s1);                                      \
    const float u1v = fmaf(-fB.y, vr1, vA1);                                    \
    const float vr2 = fmaf(fG.y, u1v, fmaf(fG.z, u0v, s2));                     \
    const float u2v = fmaf(-fB.z, vr2, vA2);                                    \
    const float vr3 = fmaf(fG.w, u2v, fmaf(fG2.x, u1v, fmaf(fG2.y, u0v, s3)));  \
    const float u3v = fmaf(-fB.w, vr3, vA3);                                    \
    const float u0 = rdl63(u0v), u1 = rdl63(u1v);                               \
    const float u2 = rdl63(u2v), u3 = rdl63(u3v);                               \
    float4 ka0 = *(const float4*)(LB + 1024 + col4);                            \
    float4 ka1 = *(const float4*)(LB + 1280 + col4);                            \
    float4 ka2 = *(const float4*)(LB + 1536 + col4);                            \
    float4 ka3 = *(const float4*)(LB + 1792 + col4);                            \
    float4 acc;                                                                 \
    acc.x = u0*ka0.x; acc.y = u0*ka0.y; acc.z = u0*ka0.z; acc.w = u0*ka0.w;     \
    acc.x = fmaf(df, acc.x, u1*ka1.x); acc.y = fmaf(df, acc.y, u1*ka1.y);       \
    acc.z = fmaf(df, acc.z, u1*ka1.z); acc.w = fmaf(df, acc.w, u1*ka1.w);       \
    acc.x = fmaf(df, acc.x, u2*ka2.x); acc.y = fmaf(df, acc.y, u2*ka2.y);       \
    acc.z = fmaf(df, acc.z, u2*ka2.z); acc.w = fmaf(df, acc.w, u2*ka2.w);       \
    acc.x = fmaf(df, acc.x, u3*ka3.x); acc.y = fmaf(df, acc.y, u3*ka3.y);       \
    acc.z = fmaf(df, acc.z, u3*ka3.z); acc.w = fmaf(df, acc.w, u3*ka3.w);       \
    { f32x2 a01 = {acc.x, acc.y}, a23 = {acc.z, acc.w};                         \
      w01 = pk_fma(df4p, w01, a01); w23 = pk_fma(df4p, w23, a23); }             \
    *(float4*)(&ldsb[cur ^ 1][sid][0]     + col4) = sq;                         \
    *(float4*)(&ldsb[cur ^ 1][4 + sid][0] + col4) = sk;                         \
    __syncthreads();                                                            \
    cur ^= 1;                                                                   \
    __builtin_amdgcn_sched_barrier(0);                                          \
  }

__global__ __launch_bounds__(256, 8)
void recur_kernel(const float* __restrict__ pq, const float* __restrict__ pk,
                  const float* __restrict__ vbeta, const float* __restrict__ band,
                  const float* __restrict__ decay, float* __restrict__ y)
{
    // 2048 blocks: sl = blk&31 (XCD = blk&7 hosts one batch), rg = blk>>5.
    const int sl   = blockIdx.x & 31;        // slice 0..31
    const int rg   = blockIdx.x >> 5;        // row group 0..63
    const int s    = sl >> 2;                // segment 0..7
    const int b    = sl & 3;                 // batch
    const int lane = threadIdx.x & 63;
    const int sid  = threadIdx.x >> 6;       // wave id = staged token id
    const int i    = rg * 4 + sid;           // row of W

    const float df  = 1.f / (1.f + expf(-decay[0]));
    const float df2 = df * df, df3 = df2 * df, df4 = df2 * df2;
    const f32x2 df4p = {df4, df4};

    const float* pqb = pq    + (size_t)b * LL * DD;
    const float* pkb = pk    + (size_t)b * LL * DD;
    const float* vbb = vbeta + (size_t)b * LL * DD;
    const float* bdb = band  + (size_t)b * LL * 4;   // LL/4 groups x 16 floats
    float* yb = y + (size_t)b * LL * DD;
    const char* pqc = (const char*)pqb;
    const char* pkc = (const char*)pkb;
    const char* vbc = (const char*)vbb;
    const char* bdc = (const char*)bdb;
    char* ybc = (char*)yb;
    const int col4 = lane * 4;               // float index within a 256-row

    const int t0    = s * SEG;
    const int start = s ? (t0 - WARM) : 0;
    const int nwarm = s ? (WARM / 4) : 0;

    f32x2 w01 = {0.f, 0.f}, w23 = {0.f, 0.f};

    __shared__ float ldsb[2][8][256];        // [buf][q0..q3,k0..k3][col] 16KB

    // staging stream: wave sid stages q(t+sid) -> row sid, k(t+sid) -> row 4+sid
    unsigned gqof = (unsigned)(start + sid) * 1024u + (unsigned)lane * 16u;
    unsigned gkof = gqof;

    // prologue: stage tokens (start .. start+3) into buffer 0
    {
        float4 a = *(const float4*)(pqc + gqof);
        float4 c = *(const float4*)(pkc + gkof);
        *(float4*)(&ldsb[0][sid][0]     + col4) = a;
        *(float4*)(&ldsb[0][4 + sid][0] + col4) = c;
        gqof += 4096u; gkof += 4096u;
        __syncthreads();
    }
    int cur = 0;

    unsigned gbof = (unsigned)(start >> 2) * 64u;
    unsigned vof  = (unsigned)start * 1024u + (unsigned)i * 4u;
    unsigned yof  = (unsigned)t0    * 1024u + (unsigned)i * 4u;

    for (int it = 0; it < nwarm; ++it) {
        STEP4LW()
    }
    for (int it = 0; it < SEG/4; ++it) {
        STEP4L(1)
    }
}

// ---------------------------------------------------------------------------
// LN: wave-per-token, DPP reduce, writes bf16 (consumed by MFMA out-GEMM).
// ---------------------------------------------------------------------------
__global__ __launch_bounds__(256)
void ln_kernel(const float* __restrict__ y, const float* __restrict__ g,
               const float* __restrict__ b, unsigned short* __restrict__ out)
{
    const int t = blockIdx.x * 4 + (threadIdx.x >> 6);
    const int lane = threadIdx.x & 63;
    const int col = lane * 4;
    const size_t base = (size_t)t * DD + col;

    float4 v4 = *(const float4*)(y + base);
    float s0 = v4.x + v4.y + v4.z + v4.w;
    float s1 = dot4f(v4, v4);
    DPP_RED6(s0) DPP_RED6(s1)
    float T0 = rdl63(s0), T1 = rdl63(s1);
    float mu = T0 * (1.f/DD);
    float rs = rsqrtf(T1 * (1.f/DD) - mu*mu + LN_EPS);

    float4 g4 = *(const float4*)(g + col);
    float4 b4 = *(const float4*)(b + col);
    ushort4 o;
    o.x = f2bf((v4.x - mu) * rs * g4.x + b4.x);
    o.y = f2bf((v4.y - mu) * rs * g4.y + b4.y);
    o.z = f2bf((v4.z - mu) * rs * g4.z + b4.z);
    o.w = f2bf((v4.w - mu) * rs * g4.w + b4.w);
    *(ushort4*)(out + base) = o;
}

// ---------------------------------------------------------------------------
extern "C" void kernel_launch(void* const* d_in, const int* in_sizes, int n_in,
                              void* d_out, int out_size, void* d_ws, size_t ws_size,
                              hipStream_t stream)
{
    const float* x      = (const float*)d_in[0];
    const float* Wq     = (const float*)d_in[1];
    const float* Wk     = (const float*)d_in[2];
    const float* Wv     = (const float*)d_in[3];
    const float* beta_w = (const float*)d_in[4];
    const float* beta_b = (const float*)d_in[5];
    const float* decay  = (const float*)d_in[6];
    const float* Wo     = (const float*)d_in[7];
    const float* bo     = (const float*)d_in[8];
    const float* ln_g   = (const float*)d_in[9];
    const float* ln_b   = (const float*)d_in[10];
    const float* lnp_g  = (const float*)d_in[11];
    const float* lnp_b  = (const float*)d_in[12];

    float* ws = (float*)d_ws;
    float* band  = ws + OFF_BAND;
    float* pq    = ws + OFF_PQ;
    float* pk    = ws + OFF_PK;
    float* v_st  = ws + OFF_V;     // scaled to beta*v by phi
    float* q_st  = ws + OFF_Y;
    float* k_st  = ws + OFF_LNY;
    float* betas = ws + OFF_BETA;

    unsigned short* xb   = (unsigned short*)(ws + OFF_PQ);   // dead before phi
    unsigned short* wb   = (unsigned short*)(ws + OFF_PK);   // dead before phi
    unsigned short* lnyb = (unsigned short*)(ws + OFF_LNY);  // k_st dead after phi
    unsigned short* wob  = (unsigned short*)(ws + OFF_V);    // v dead after recur

    // bf16 casts: x (+ betas) and the three projection weights
    cast_all_kernel<<<1024 + 192, 256, 0, stream>>>(x, Wq, Wk, Wv, beta_w, beta_b,
                                                    xb, wb, betas);

    // MFMA q/k/v projections (fp32 out)
    gemm_qkv_bf16_kernel<<<dim3(NT/64, DD/64, 3), 256, 0, stream>>>(
        xb, wb, q_st, k_st, v_st);

    // phi (+ v *= beta in place; betas from cast_all)
    phi_kernel<<<NT/4, 256, 0, stream>>>(q_st, k_st, v_st, betas,
                                         lnp_g, lnp_b, pq, pk);

    // depth-3 group-packed Gram band
    band_kernel<<<NT/4, 256, 0, stream>>>(pq, pk, betas, decay, band);

    // segmented fast-weight recurrence (8 waves/SIMD, LDS-shared STEP4)
    recur_kernel<<<2048, 256, 0, stream>>>(pq, pk, v_st, band, decay, ws + OFF_Y);

    // final LN -> bf16, cast Wo (v region dead), MFMA output projection
    ln_kernel<<<NT/4, 256, 0, stream>>>(ws + OFF_Y, ln_g, ln_b, lnyb);
    cast_wo_kernel<<<64, 256, 0, stream>>>(Wo, wob);
    gemm_out_bf16_kernel<<<dim3(NT/64, DD/64), 256, 0, stream>>>(
        lnyb, wob, bo, (float*)d_out);
}

// Round 20
// 122.189 us; speedup vs baseline: 1.0450x; 1.0450x over previous
//
#include <hip/hip_runtime.h>
#include <math.h>

#define BB 4
#define LL 1024
#define DD 256
#define NT (BB*LL)          // 4096 tokens
#define LN_EPS 1e-5f

#define SEG 128             // segment length (8 per batch)
#define WARM 32             // warmup steps; df^32 = 4e-5 -> truncation negligible

// workspace layout (floats). band FIRST so end-of-segment prefetch overrun
// lands in a following owned region. bf16 staging buffers overlay regions
// that are dead at their time of use.
#define OFF_BAND 0                      // NT*4 used: {G1,H1,beta,0}
#define OFF_PQ   (8*NT)
#define OFF_PK   (OFF_PQ + NT*DD)
#define OFF_V    (OFF_PK + NT*DD)       // becomes beta*v after phi (in-place)
#define OFF_Y    (OFF_V + NT*DD)        // also q staging before phi
#define OFF_LNY  (OFF_Y + NT*DD)        // also k staging before phi
#define OFF_BETA (OFF_LNY + NT*DD)

typedef __attribute__((ext_vector_type(8))) short short8;
typedef __attribute__((ext_vector_type(4))) float f32x4;
typedef __attribute__((ext_vector_type(2))) float f32x2;

// Builtin DPP add (compiler inserts DPP hazard nops) — off the hot path.
#define DPP_ADD(x, ctrl) ((x) + __uint_as_float(__builtin_amdgcn_update_dpp( \
        0u, __float_as_uint(x), (ctrl), 0xf, 0xf, true)))
#define DPP_RED6(x) x = DPP_ADD(x, 0x111); x = DPP_ADD(x, 0x112); \
                    x = DPP_ADD(x, 0x114); x = DPP_ADD(x, 0x118); \
                    x = DPP_ADD(x, 0x142); x = DPP_ADD(x, 0x143);

__device__ __forceinline__ float dot4f(float4 a, float4 b) {
    return fmaf(a.x, b.x, a.y * b.y) + fmaf(a.z, b.z, a.w * b.w);
}
__device__ __forceinline__ float rdl63(float x) {
    return __uint_as_float((unsigned)__builtin_amdgcn_readlane(__float_as_uint(x), 63));
}
__device__ __forceinline__ unsigned short f2bf(float f) {
    unsigned u = __float_as_uint(f);
    unsigned r = (u + 0x7fffu + ((u >> 16) & 1u)) >> 16;   // RNE
    return (unsigned short)r;
}

// Packed fp32 (VOP3P, dual-SIMD) — hipcc won't auto-generate these.
__device__ __forceinline__ f32x2 pk_mul(f32x2 a, f32x2 b) {
    f32x2 d; asm("v_pk_mul_f32 %0, %1, %2" : "=v"(d) : "v"(a), "v"(b)); return d;
}
__device__ __forceinline__ f32x2 pk_fma(f32x2 a, f32x2 b, f32x2 c) {
    f32x2 d; asm("v_pk_fma_f32 %0, %1, %2, %3" : "=v"(d) : "v"(a), "v"(b), "v"(c)); return d;
}
__device__ __forceinline__ float dot4pk(f32x2 w01, f32x2 w23, float4 b) {
    f32x2 blo = {b.x, b.y}, bhi = {b.z, b.w};
    f32x2 t = pk_mul(w01, blo);
    t = pk_fma(w23, bhi, t);
    return t.x + t.y;
}

// ---------------------------------------------------------------------------
// cast_all: x -> bf16 xb (+ betas via DPP reduce), Wq/Wk/Wv -> bf16 wb.
// ---------------------------------------------------------------------------
__global__ __launch_bounds__(256)
void cast_all_kernel(const float* __restrict__ x, const float* __restrict__ Wq,
                     const float* __restrict__ Wk, const float* __restrict__ Wv,
                     const float* __restrict__ beta_w, const float* __restrict__ beta_b,
                     unsigned short* __restrict__ xb, unsigned short* __restrict__ wb,
                     float* __restrict__ betas)
{
    int b = blockIdx.x;
    if (b < 1024) {
        const int lane = threadIdx.x & 63;
        const int t = b * 4 + (threadIdx.x >> 6);
        size_t idx = (size_t)b * 1024 + (size_t)threadIdx.x * 4;
        float4 v = *(const float4*)(x + idx);
        ushort4 o;
        o.x = f2bf(v.x); o.y = f2bf(v.y); o.z = f2bf(v.z); o.w = f2bf(v.w);
        *(ushort4*)(xb + idx) = o;
        float4 bw4 = *(const float4*)(beta_w + lane * 4);
        float bd = dot4f(v, bw4);
        DPP_RED6(bd)
        if (lane == 63) betas[t] = 1.f / (1.f + expf(-(bd + beta_b[0])));
    } else {
        int wsel = (b - 1024) >> 6;
        const float* src = (wsel == 0) ? Wq : (wsel == 1) ? Wk : Wv;
        unsigned short* dst = wb + (size_t)wsel * 65536;
        size_t idx = (size_t)((b - 1024) & 63) * 1024 + (size_t)threadIdx.x * 4;
        float4 v = *(const float4*)(src + idx);
        ushort4 o;
        o.x = f2bf(v.x); o.y = f2bf(v.y); o.z = f2bf(v.z); o.w = f2bf(v.w);
        *(ushort4*)(dst + idx) = o;
    }
}

__global__ __launch_bounds__(256)
void cast_wo_kernel(const float* __restrict__ Wo, unsigned short* __restrict__ wob)
{
    size_t idx = (size_t)blockIdx.x * 1024 + (size_t)threadIdx.x * 4;
    float4 v = *(const float4*)(Wo + idx);
    ushort4 o;
    o.x = f2bf(v.x); o.y = f2bf(v.y); o.z = f2bf(v.z); o.w = f2bf(v.w);
    *(ushort4*)(wob + idx) = o;
}

// ---------------------------------------------------------------------------
// MFMA bf16 GEMM (as R12-R18).
// ---------------------------------------------------------------------------
__device__ __forceinline__
void gemm_bf16_body(const unsigned short* __restrict__ A,
                    const unsigned short* __restrict__ W,
                    const float* __restrict__ bias, float* __restrict__ C,
                    int tile_m, int tile_n)
{
    const int w = threadIdx.x >> 6;
    const int l = threadIdx.x & 63;
    const int wm = (w >> 1) * 32, wn = (w & 1) * 32;
    const int kb = (l >> 4) * 8;

    const unsigned short* Ap = A + (size_t)(tile_m + wm + (l & 15)) * DD + kb;
    const unsigned short* Wp = W + (size_t)(tile_n + wn + (l & 15)) * DD + kb;

    f32x4 acc00 = {0.f,0.f,0.f,0.f}, acc01 = {0.f,0.f,0.f,0.f};
    f32x4 acc10 = {0.f,0.f,0.f,0.f}, acc11 = {0.f,0.f,0.f,0.f};

    #pragma unroll
    for (int ks = 0; ks < DD; ks += 32) {
        short8 a0 = *(const short8*)(Ap + ks);
        short8 a1 = *(const short8*)(Ap + 16*DD + ks);
        short8 b0 = *(const short8*)(Wp + ks);
        short8 b1 = *(const short8*)(Wp + 16*DD + ks);
        acc00 = __builtin_amdgcn_mfma_f32_16x16x32_bf16(a0, b0, acc00, 0, 0, 0);
        acc01 = __builtin_amdgcn_mfma_f32_16x16x32_bf16(a0, b1, acc01, 0, 0, 0);
        acc10 = __builtin_amdgcn_mfma_f32_16x16x32_bf16(a1, b0, acc10, 0, 0, 0);
        acc11 = __builtin_amdgcn_mfma_f32_16x16x32_bf16(a1, b1, acc11, 0, 0, 0);
    }

    const int r0 = (l >> 4) * 4;
    const int c0 = l & 15;
    #pragma unroll
    for (int i = 0; i < 2; ++i) {
        #pragma unroll
        for (int j = 0; j < 2; ++j) {
            const f32x4 a = (i==0) ? (j==0?acc00:acc01) : (j==0?acc10:acc11);
            int row = tile_m + wm + i*16 + r0;
            int col = tile_n + wn + j*16 + c0;
            float bv = bias ? bias[col] : 0.f;
            #pragma unroll
            for (int r = 0; r < 4; ++r)
                C[(size_t)(row + r) * DD + col] = a[r] + bv;
        }
    }
}

__global__ __launch_bounds__(256)
void gemm_qkv_bf16_kernel(const unsigned short* __restrict__ xb,
                          const unsigned short* __restrict__ wb,
                          float* __restrict__ q, float* __restrict__ k,
                          float* __restrict__ v)
{
    const unsigned short* W = wb + (size_t)blockIdx.z * 65536;
    float* C = (blockIdx.z == 0) ? q : (blockIdx.z == 1) ? k : v;
    gemm_bf16_body(xb, W, nullptr, C, blockIdx.x * 64, blockIdx.y * 64);
}

__global__ __launch_bounds__(256)
void gemm_out_bf16_kernel(const unsigned short* __restrict__ lnyb,
                          const unsigned short* __restrict__ wob,
                          const float* __restrict__ bo, float* __restrict__ C)
{
    gemm_bf16_body(lnyb, wob, bo, C, blockIdx.x * 64, blockIdx.y * 64);
}

// ---------------------------------------------------------------------------
// phi: wave-per-token. pq = LN(elu(q)+1), pk = LN(elu(k)+1), v *= beta.
// ---------------------------------------------------------------------------
__global__ __launch_bounds__(256)
void phi_kernel(const float* __restrict__ q, const float* __restrict__ k,
                float* __restrict__ v, const float* __restrict__ betas,
                const float* __restrict__ lnp_g, const float* __restrict__ lnp_b,
                float* __restrict__ pq, float* __restrict__ pk)
{
    const int t = blockIdx.x * 4 + (threadIdx.x >> 6);
    const int lane = threadIdx.x & 63;
    const int col = lane * 4;
    const size_t base = (size_t)t * DD + col;

    float4 q4 = *(const float4*)(q + base);
    float4 k4 = *(const float4*)(k + base);

    float4 eq, ek;
    eq.x = q4.x > 0.f ? q4.x + 1.f : expf(q4.x);
    eq.y = q4.y > 0.f ? q4.y + 1.f : expf(q4.y);
    eq.z = q4.z > 0.f ? q4.z + 1.f : expf(q4.z);
    eq.w = q4.w > 0.f ? q4.w + 1.f : expf(q4.w);
    ek.x = k4.x > 0.f ? k4.x + 1.f : expf(k4.x);
    ek.y = k4.y > 0.f ? k4.y + 1.f : expf(k4.y);
    ek.z = k4.z > 0.f ? k4.z + 1.f : expf(k4.z);
    ek.w = k4.w > 0.f ? k4.w + 1.f : expf(k4.w);

    float s0 = eq.x + eq.y + eq.z + eq.w;
    float s1 = dot4f(eq, eq);
    float s2 = ek.x + ek.y + ek.z + ek.w;
    float s3 = dot4f(ek, ek);

    DPP_RED6(s0) DPP_RED6(s1) DPP_RED6(s2) DPP_RED6(s3)
    float T0 = rdl63(s0), T1 = rdl63(s1), T2 = rdl63(s2), T3 = rdl63(s3);

    float mu_q = T0 * (1.f/DD);
    float rs_q = rsqrtf(T1 * (1.f/DD) - mu_q*mu_q + LN_EPS);
    float mu_k = T2 * (1.f/DD);
    float rs_k = rsqrtf(T3 * (1.f/DD) - mu_k*mu_k + LN_EPS);
    float beta = betas[t];

    float4 g4 = *(const float4*)(lnp_g + col);
    float4 b4 = *(const float4*)(lnp_b + col);
    float4 oq, ok;
    oq.x = (eq.x - mu_q) * rs_q * g4.x + b4.x;
    oq.y = (eq.y - mu_q) * rs_q * g4.y + b4.y;
    oq.z = (eq.z - mu_q) * rs_q * g4.z + b4.z;
    oq.w = (eq.w - mu_q) * rs_q * g4.w + b4.w;
    ok.x = (ek.x - mu_k) * rs_k * g4.x + b4.x;
    ok.y = (ek.y - mu_k) * rs_k * g4.y + b4.y;
    ok.z = (ek.z - mu_k) * rs_k * g4.z + b4.z;
    ok.w = (ek.w - mu_k) * rs_k * g4.w + b4.w;
    *(float4*)(pq + base) = oq;
    *(float4*)(pk + base) = ok;

    float4 v4 = *(const float4*)(v + base);
    v4.x *= beta; v4.y *= beta; v4.z *= beta; v4.w *= beta;
    *(float4*)(v + base) = v4;
}

// ---------------------------------------------------------------------------
// band (compact, depth-1): band[g] = {G1, H1, beta, 0}.
// ---------------------------------------------------------------------------
__global__ __launch_bounds__(256)
void band_kernel(const float* __restrict__ pq, const float* __restrict__ pk,
                 const float* __restrict__ betas, float* __restrict__ band)
{
    const int wv = threadIdx.x >> 6, lane = threadIdx.x & 63;
    const int g = blockIdx.x * 4 + wv;       // global token 0..NT-1
    const int tt = g & (LL - 1);             // token index within batch
    const int col = lane * 4;

    float4 kv = *(const float4*)(pk + (size_t)g * DD + col);
    float4 qv = *(const float4*)(pq + (size_t)g * DD + col);

    float gg1 = 0.f, hh1 = 0.f;
    if (tt >= 1) { float4 km = *(const float4*)(pk + (size_t)(g-1) * DD + col);
                   gg1 = dot4f(km, kv); hh1 = dot4f(km, qv); }

    DPP_RED6(gg1) DPP_RED6(hh1)

    if (lane == 63) {
        float4 a = make_float4(gg1, hh1, betas[g], 0.f);
        *(float4*)(band + (size_t)g * 4) = a;
    }
}

// ---------------------------------------------------------------------------
// Segmented fast-weight recurrence, 8 waves/SIMD, LDS-shared q/k (R18 form:
// the proven 85.6us configuration). R19's STEP4 regressed (extra LDS reads
// outweighed saved barriers); R17 showed fewer VALU inst alone doesn't help.
// Per STEP2: block stages next 2 tokens' q+k (4KB, wave sid stages stream
// sid) into double-buffered LDS; waves ds_read_b128. One __syncthreads per
// step; 8 blocks/CU hide it. Depth-1 band recursion in-lane on lane 63.
// ---------------------------------------------------------------------------
#define RED_ROUND4(mod, pre)                                                    \
    asm(pre                                                                     \
        "v_add_f32 %0, %0, %0 " mod " bound_ctrl:0\n\t"                         \
        "v_add_f32 %1, %1, %1 " mod " bound_ctrl:0\n\t"                         \
        "v_add_f32 %2, %2, %2 " mod " bound_ctrl:0\n\t"                         \
        "v_add_f32 %3, %3, %3 " mod " bound_ctrl:0"                             \
        : "+v"(s0), "+v"(s1), "+v"(p0), "+v"(p1));

#define RED_ROUND2(mod)                                                         \
    asm("s_nop 1\n\t"                                                           \
        "v_add_f32 %0, %0, %0 " mod " bound_ctrl:0\n\t"                         \
        "v_add_f32 %1, %1, %1 " mod " bound_ctrl:0"                             \
        : "+v"(s0), "+v"(s1));

// Main step: reads q0,q1,k0,k1 from LDS[cur]; stages next tokens to LDS[cur^1].
#define STEP2L(ST)                                                              \
  {                                                                             \
    const float* LB = &ldsb[cur][0][0];                                         \
    float4 kk0 = *(const float4*)(LB + 512 + col4);                             \
    float4 kk1 = *(const float4*)(LB + 768 + col4);                             \
    float4 qq0 = *(const float4*)(LB +       col4);                             \
    float4 qq1 = *(const float4*)(LB + 256 + col4);                             \
    float4 sreg = *(const float4*)(gsrc + gof); gof += 2048u;                   \
    float s0 = dot4pk(w01, w23, kk0),      p0 = dot4pk(w01, w23, qq0);          \
    float s1 = dot4pk(w01, w23, kk1) * df, p1 = dot4pk(w01, w23, qq1) * df;     \
    RED_ROUND4("row_shr:1",   "s_nop 1\n\t")                                    \
    RED_ROUND4("row_shr:2",   "")                                               \
    RED_ROUND4("row_shr:4",   "")                                               \
    RED_ROUND4("row_shr:8",   "")                                               \
    RED_ROUND4("row_bcast:15","")                                               \
    RED_ROUND4("row_bcast:31","")                                               \
    asm volatile("s_nop 1");                                                    \
    /* in-lane recursion: valid in lane 63 (band/v are wave-uniform) */         \
    const float u0v = fmaf(-bA[0].z, s0, vA[0]);                                \
    const float rr0 = p0;                                                       \
    const float vr1 = fmaf(bA[1].x, u0v, s1);                                   \
    const float rr1 = fmaf(bA[1].y, u0v, p1);                                   \
    const float u1v = fmaf(-bA[1].z, vr1, vA[1]);                               \
    bA[0] = *(const float4*)(bdc + bof);                                        \
    bA[1] = *(const float4*)(bdc + bof + 16);                                   \
    vA[0] = *(const float*)(vbc + vof);                                         \
    vA[1] = *(const float*)(vbc + vof + 1024);                                  \
    bof += 32u; vof += 2048u;                                                   \
    const float u0 = rdl63(u0v), u1 = rdl63(u1v);                               \
    const float ud0 = df * u0;                                                  \
    float4 acc;                                                                 \
    acc.x = ud0*kk0.x; acc.y = ud0*kk0.y; acc.z = ud0*kk0.z; acc.w = ud0*kk0.w; \
    acc.x = fmaf(u1, kk1.x, acc.x); acc.y = fmaf(u1, kk1.y, acc.y);             \
    acc.z = fmaf(u1, kk1.z, acc.z); acc.w = fmaf(u1, kk1.w, acc.w);             \
    { f32x2 a01 = {acc.x, acc.y}, a23 = {acc.z, acc.w};                         \
      w01 = pk_fma(df2p, w01, a01); w23 = pk_fma(df2p, w23, a23); }             \
    if (ST) {                                                                   \
        if (lane == 63) {                                                       \
            *(float*)(ybc + yof)        = rr0;                                  \
            *(float*)(ybc + yof + 1024) = rr1;                                  \
        }                                                                       \
    }                                                                           \
    yof += 2048u;                                                               \
    *(float4*)(&ldsb[cur ^ 1][0][0] + (sid << 8) + col4) = sreg;                \
    __syncthreads();                                                            \
    cur ^= 1;                                                                   \
    __builtin_amdgcn_sched_barrier(0);                                          \
  }

// Warmup step: k-only compute (no q reads / p chains / stores); still stages.
#define STEP2LW()                                                               \
  {                                                                             \
    const float* LB = &ldsb[cur][0][0];                                         \
    float4 kk0 = *(const float4*)(LB + 512 + col4);                             \
    float4 kk1 = *(const float4*)(LB + 768 + col4);                             \
    float4 sreg = *(const float4*)(gsrc + gof); gof += 2048u;                   \
    float s0 = dot4pk(w01, w23, kk0);                                           \
    float s1 = dot4pk(w01, w23, kk1) * df;                                      \
    RED_ROUND2("row_shr:1")                                                     \
    RED_ROUND2("row_shr:2")                                                     \
    RED_ROUND2("row_shr:4")                                                     \
    RED_ROUND2("row_shr:8")                                                     \
    RED_ROUND2("row_bcast:15")                                                  \
    RED_ROUND2("row_bcast:31")                                                  \
    asm volatile("s_nop 1");                                                    \
    const float u0v = fmaf(-bA[0].z, s0, vA[0]);                                \
    const float vr1 = fmaf(bA[1].x, u0v, s1);                                   \
    const float u1v = fmaf(-bA[1].z, vr1, vA[1]);                               \
    bA[0] = *(const float4*)(bdc + bof);                                        \
    bA[1] = *(const float4*)(bdc + bof + 16);                                   \
    vA[0] = *(const float*)(vbc + vof);                                         \
    vA[1] = *(const float*)(vbc + vof + 1024);                                  \
    bof += 32u; vof += 2048u;                                                   \
    const float u0 = rdl63(u0v), u1 = rdl63(u1v);                               \
    const float ud0 = df * u0;                                                  \
    float4 acc;                                                                 \
    acc.x = ud0*kk0.x; acc.y = ud0*kk0.y; acc.z = ud0*kk0.z; acc.w = ud0*kk0.w; \
    acc.x = fmaf(u1, kk1.x, acc.x); acc.y = fmaf(u1, kk1.y, acc.y);             \
    acc.z = fmaf(u1, kk1.z, acc.z); acc.w = fmaf(u1, kk1.w, acc.w);             \
    { f32x2 a01 = {acc.x, acc.y}, a23 = {acc.z, acc.w};                         \
      w01 = pk_fma(df2p, w01, a01); w23 = pk_fma(df2p, w23, a23); }             \
    *(float4*)(&ldsb[cur ^ 1][0][0] + (sid << 8) + col4) = sreg;                \
    __syncthreads();                                                            \
    cur ^= 1;                                                                   \
    __builtin_amdgcn_sched_barrier(0);                                          \
  }

__global__ __launch_bounds__(256, 8)
void recur_kernel(const float* __restrict__ pq, const float* __restrict__ pk,
                  const float* __restrict__ vbeta, const float* __restrict__ band,
                  const float* __restrict__ decay, float* __restrict__ y)
{
    // 2048 blocks: sl = blk&31 (XCD = blk&7 hosts one batch), rg = blk>>5.
    const int sl   = blockIdx.x & 31;        // slice 0..31
    const int rg   = blockIdx.x >> 5;        // row group 0..63
    const int s    = sl >> 2;                // segment 0..7
    const int b    = sl & 3;                 // batch
    const int lane = threadIdx.x & 63;
    const int sid  = threadIdx.x >> 6;       // wave id = staged stream id
    const int i    = rg * 4 + sid;           // row of W

    const float df  = 1.f / (1.f + expf(-decay[0]));
    const float df2 = df * df;
    const f32x2 df2p = {df2, df2};

    const float* pqb = pq    + (size_t)b * LL * DD;
    const float* pkb = pk    + (size_t)b * LL * DD;
    const float* vbb = vbeta + (size_t)b * LL * DD;
    const float* bdb = band  + (size_t)b * LL * 4;
    float* yb = y + (size_t)b * LL * DD;
    const char* pqc = (const char*)pqb;
    const char* pkc = (const char*)pkb;
    const char* vbc = (const char*)vbb;
    const char* bdc = (const char*)bdb;
    char* ybc = (char*)yb;
    const int col4 = lane * 4;               // float index within a 256-row

    const int t0    = s * SEG;
    const int start = s ? (t0 - WARM) : 0;
    const int nwarm = s ? (WARM / 2) : 0;

    f32x2 w01 = {0.f, 0.f}, w23 = {0.f, 0.f};

    __shared__ float ldsb[2][4][256];        // [buf][q0,q1,k0,k1][col] 8KB

    float4 bA[2]; float vA[2];
    #pragma unroll
    for (int p = 0; p < 2; ++p) {
        bA[p] = *(const float4*)(bdb + (size_t)(start+p) * 4);
        vA[p] = vbb[(size_t)(start+p) * DD + i];
    }

    // staging stream: wave 0/1 -> q tokens (even/odd), wave 2/3 -> k.
    const char* gsrc = (sid < 2) ? pqc : pkc;
    unsigned gof = (unsigned)(start + (sid & 1)) * 1024u + (unsigned)lane * 16u;

    // prologue: stage tokens (start, start+1) into buffer 0
    {
        float4 s0v = *(const float4*)(gsrc + gof);
        *(float4*)(&ldsb[0][0][0] + (sid << 8) + col4) = s0v;
        gof += 2048u;
        __syncthreads();
    }
    int cur = 0;

    unsigned vof = (unsigned)(start+2) * 1024u + (unsigned)i * 4u;
    unsigned bof = (unsigned)(start+2) * 16u;
    unsigned yof = (unsigned)t0        * 1024u + (unsigned)i * 4u;

    for (int it = 0; it < nwarm; ++it) {
        STEP2LW()
    }
    for (int it = 0; it < SEG/2; ++it) {
        STEP2L(1)
    }
}

// ---------------------------------------------------------------------------
// LN: wave-per-token, DPP reduce, writes bf16 (consumed by MFMA out-GEMM).
// ---------------------------------------------------------------------------
__global__ __launch_bounds__(256)
void ln_kernel(const float* __restrict__ y, const float* __restrict__ g,
               const float* __restrict__ b, unsigned short* __restrict__ out)
{
    const int t = blockIdx.x * 4 + (threadIdx.x >> 6);
    const int lane = threadIdx.x & 63;
    const int col = lane * 4;
    const size_t base = (size_t)t * DD + col;

    float4 v4 = *(const float4*)(y + base);
    float s0 = v4.x + v4.y + v4.z + v4.w;
    float s1 = dot4f(v4, v4);
    DPP_RED6(s0) DPP_RED6(s1)
    float T0 = rdl63(s0), T1 = rdl63(s1);
    float mu = T0 * (1.f/DD);
    float rs = rsqrtf(T1 * (1.f/DD) - mu*mu + LN_EPS);

    float4 g4 = *(const float4*)(g + col);
    float4 b4 = *(const float4*)(b + col);
    ushort4 o;
    o.x = f2bf((v4.x - mu) * rs * g4.x + b4.x);
    o.y = f2bf((v4.y - mu) * rs * g4.y + b4.y);
    o.z = f2bf((v4.z - mu) * rs * g4.z + b4.z);
    o.w = f2bf((v4.w - mu) * rs * g4.w + b4.w);
    *(ushort4*)(out + base) = o;
}

// ---------------------------------------------------------------------------
extern "C" void kernel_launch(void* const* d_in, const int* in_sizes, int n_in,
                              void* d_out, int out_size, void* d_ws, size_t ws_size,
                              hipStream_t stream)
{
    const float* x      = (const float*)d_in[0];
    const float* Wq     = (const float*)d_in[1];
    const float* Wk     = (const float*)d_in[2];
    const float* Wv     = (const float*)d_in[3];
    const float* beta_w = (const float*)d_in[4];
    const float* beta_b = (const float*)d_in[5];
    const float* decay  = (const float*)d_in[6];
    const float* Wo     = (const float*)d_in[7];
    const float* bo     = (const float*)d_in[8];
    const float* ln_g   = (const float*)d_in[9];
    const float* ln_b   = (const float*)d_in[10];
    const float* lnp_g  = (const float*)d_in[11];
    const float* lnp_b  = (const float*)d_in[12];

    float* ws = (float*)d_ws;
    float* band  = ws + OFF_BAND;
    float* pq    = ws + OFF_PQ;
    float* pk    = ws + OFF_PK;
    float* v_st  = ws + OFF_V;     // scaled to beta*v by phi
    float* q_st  = ws + OFF_Y;
    float* k_st  = ws + OFF_LNY;
    float* betas = ws + OFF_BETA;

    unsigned short* xb   = (unsigned short*)(ws + OFF_PQ);   // dead before phi
    unsigned short* wb   = (unsigned short*)(ws + OFF_PK);   // dead before phi
    unsigned short* lnyb = (unsigned short*)(ws + OFF_LNY);  // k_st dead after phi
    unsigned short* wob  = (unsigned short*)(ws + OFF_V);    // v dead after recur

    // bf16 casts: x (+ betas) and the three projection weights
    cast_all_kernel<<<1024 + 192, 256, 0, stream>>>(x, Wq, Wk, Wv, beta_w, beta_b,
                                                    xb, wb, betas);

    // MFMA q/k/v projections (fp32 out)
    gemm_qkv_bf16_kernel<<<dim3(NT/64, DD/64, 3), 256, 0, stream>>>(
        xb, wb, q_st, k_st, v_st);

    // phi (+ v *= beta in place; betas from cast_all)
    phi_kernel<<<NT/4, 256, 0, stream>>>(q_st, k_st, v_st, betas,
                                         lnp_g, lnp_b, pq, pk);

    // compact Gram band (depth-1)
    band_kernel<<<NT/4, 256, 0, stream>>>(pq, pk, betas, band);

    // segmented fast-weight recurrence (8 waves/SIMD, LDS-shared q/k)
    recur_kernel<<<2048, 256, 0, stream>>>(pq, pk, v_st, band, decay, ws + OFF_Y);

    // final LN -> bf16, cast Wo (v region dead), MFMA output projection
    ln_kernel<<<NT/4, 256, 0, stream>>>(ws + OFF_Y, ln_g, ln_b, lnyb);
    cast_wo_kernel<<<64, 256, 0, stream>>>(Wo, wob);
    gemm_out_bf16_kernel<<<dim3(NT/64, DD/64), 256, 0, stream>>>(
        lnyb, wob, bo, (float*)d_out);
}